// Round 11
// baseline (1752.016 us; speedup 1.0000x reference)
//
#include <hip/hip_runtime.h>
#include <hip/hip_bf16.h>
#include <math.h>

#define BS 8192
#define HID 256
#define SPB1 8

// ---- workspace layout (float element offsets) ----
#define WT1_OFF 0
#define WT2_OFF 65536
#define WT3_OFF 131072
#define WT0_OFF 196608
#define S_OFF   204800
#define C_OFF   (S_OFF + 4 * BS * HID)
#define G_OFF   (C_OFF + 4 * BS * HID)
#define WBT_OFF (G_OFF + BS * 16)
// WBT region: brick-swizzled W: 3 lay x 2 (hi,lo) x 8 nt x 16 kb x 64 lanes x 8 shorts

typedef __attribute__((ext_vector_type(8))) short bf16x8;
typedef __attribute__((ext_vector_type(16))) float f32x16;
#define MFMA32(A, B, C) __builtin_amdgcn_mfma_f32_32x32x16_bf16(A, B, C, 0, 0, 0)

__device__ __forceinline__ ushort bf16_rne(float x) {
    unsigned u = __float_as_uint(x);
    unsigned r = u + 0x7FFFu + ((u >> 16) & 1u);
    return (ushort)(r >> 16);
}
__device__ __forceinline__ void bsplit(float x, ushort& hi, ushort& lo) {
    hi = bf16_rne(x);
    float hf = __uint_as_float(((unsigned)hi) << 16);
    lo = bf16_rne(x - hf);
}

// packed split via v_cvt_pk_bf16_f32 (gfx950)
__device__ __forceinline__ uint pk2(float a, float b) {
    __hip_bfloat162 h = __float22bfloat162_rn(float2{a, b});
    uint u; __builtin_memcpy(&u, &h, 4); return u;
}
__device__ __forceinline__ void split2(float a, float b, uint& hp, uint& lp) {
    hp = pk2(a, b);
    float ha = __uint_as_float(hp << 16);
    float hb = __uint_as_float(hp & 0xFFFF0000u);
    lp = pk2(a - ha, b - hb);
}
__device__ __forceinline__ void split4v(const float* v, uint2& H, uint2& L) {
    split2(v[0], v[1], H.x, L.x);
    split2(v[2], v[3], H.y, L.y);
}

__device__ __forceinline__ void silu_derivs(float a, float& h, float& sp, float& fpp) {
    float sig = 1.0f / (1.0f + __expf(-a));
    float om  = 1.0f - sig;
    h   = a * sig;
    sp  = sig * (1.0f + a * om);                       // silu'
    fpp = sig * om * (2.0f + a * (1.0f - 2.0f * sig)); // silu''
}

// ---------------- kernel 0: weight transposes + bf16 brick swizzle ----------------
__global__ void k_transpose(const float* __restrict__ W0, const float* __restrict__ W1,
                            const float* __restrict__ W2, const float* __restrict__ W3,
                            float* __restrict__ ws) {
    float* WT1 = ws + WT1_OFF;
    float* WT2 = ws + WT2_OFF;
    float* WT3 = ws + WT3_OFF;
    float* WT0 = ws + WT0_OFF;
    ushort* WBT = (ushort*)(ws + WBT_OFF);
    int o = blockIdx.x;      // 0..255 (output col)
    int t = threadIdx.x;     // 0..255 (input row k)
    int which = blockIdx.y;  // 0..3
    if (which < 3) {
        const float* W = (which == 0) ? W1 : (which == 1) ? W2 : W3;
        float* WT = (which == 0) ? WT1 : (which == 1) ? WT2 : WT3;
        float v = W[t * 256 + o];
        WT[o * 256 + t] = v;
        ushort h, l;
        bsplit(v, h, l);
        const int ntg = o >> 5, ln0 = o & 31;
        const int kb = t >> 4, hfb = (t >> 3) & 1, j = t & 7;
        const int laneidx = ln0 + 32 * hfb;
        WBT[(((which * 2 + 0) * 128) + ntg * 16 + kb) * 512 + laneidx * 8 + j] = h;
        WBT[(((which * 2 + 1) * 128) + ntg * 16 + kb) * 512 + laneidx * 8 + j] = l;
    } else if (t < 32) {
        WT0[o * 32 + t] = W0[t * 256 + o]; // WT0[i][k] = W0[k][i]
    }
}

// ---------------- kernel 1: forward + backward (8 samples/block) ----------------
__device__ __forceinline__ void fwd_layer(int L, int t, int m0,
        const float (*Hin)[SPB1], float (*Hout)[SPB1],
        const float* __restrict__ W, const float* __restrict__ b,
        float* __restrict__ f2, float* __restrict__ S)
{
    float acc[SPB1];
    #pragma unroll
    for (int s = 0; s < SPB1; ++s) acc[s] = b[t];
    const float4* H4 = (const float4*)&Hin[0][0];
    #pragma unroll 8
    for (int i = 0; i < 256; ++i) {
        float w = W[i * 256 + t];
        float4 h0 = H4[i * 2 + 0];
        float4 h1 = H4[i * 2 + 1];
        acc[0] += h0.x * w; acc[1] += h0.y * w; acc[2] += h0.z * w; acc[3] += h0.w * w;
        acc[4] += h1.x * w; acc[5] += h1.y * w; acc[6] += h1.z * w; acc[7] += h1.w * w;
    }
    #pragma unroll
    for (int s = 0; s < SPB1; ++s) {
        float h, sp, fpp;
        silu_derivs(acc[s], h, sp, fpp);
        Hout[t][s] = h;
        S[(L * BS + m0 + s) * HID + t] = sp;
        f2[s] = fpp;
    }
}

__device__ __forceinline__ void bwd_layer(int L, int t, int m0,
        const float (*Din)[SPB1], float (*Dout)[SPB1],
        const float* __restrict__ WT,
        const float* __restrict__ f2,
        const float* __restrict__ S, float* __restrict__ C)
{
    float acc[SPB1];
    #pragma unroll
    for (int s = 0; s < SPB1; ++s) acc[s] = 0.0f;
    const float4* D4 = (const float4*)&Din[0][0];
    #pragma unroll 8
    for (int o = 0; o < 256; ++o) {
        float w = WT[o * 256 + t];
        float4 d0 = D4[o * 2 + 0];
        float4 d1 = D4[o * 2 + 1];
        acc[0] += d0.x * w; acc[1] += d0.y * w; acc[2] += d0.z * w; acc[3] += d0.w * w;
        acc[4] += d1.x * w; acc[5] += d1.y * w; acc[6] += d1.z * w; acc[7] += d1.w * w;
    }
    #pragma unroll
    for (int s = 0; s < SPB1; ++s) {
        float dh = acc[s];
        float sl = S[(L * BS + m0 + s) * HID + t];
        C[(L * BS + m0 + s) * HID + t] = dh * f2[s];
        Dout[t][s] = dh * sl;  // delta_a
    }
}

__global__ __launch_bounds__(256) void k_stage1(
    const float* __restrict__ z,
    const float* __restrict__ W0, const float* __restrict__ b0,
    const float* __restrict__ W1, const float* __restrict__ b1,
    const float* __restrict__ W2, const float* __restrict__ b2,
    const float* __restrict__ W3, const float* __restrict__ b3,
    const float* __restrict__ W4,
    const float* __restrict__ WT0, const float* __restrict__ WT1,
    const float* __restrict__ WT2, const float* __restrict__ WT3,
    float* __restrict__ S, float* __restrict__ C, float* __restrict__ G)
{
    __shared__ __align__(16) float Zt[SPB1][32];
    __shared__ __align__(16) float Ha[256][SPB1];
    __shared__ __align__(16) float Hb[256][SPB1];
    const int t  = threadIdx.x;
    const int m0 = blockIdx.x * SPB1;
    float f2a[3][SPB1];   // silu'' layers 0..2: same-thread produce/consume

    Zt[t >> 5][t & 31] = z[(m0 + (t >> 5)) * 32 + (t & 31)];
    __syncthreads();

    // ---- layer 1: a1 = z @ W0 + b0 ----
    {
        float acc[SPB1];
        #pragma unroll
        for (int s = 0; s < SPB1; ++s) acc[s] = b0[t];
        #pragma unroll 8
        for (int i = 0; i < 32; ++i) {
            float w = W0[i * 256 + t];
            #pragma unroll
            for (int s = 0; s < SPB1; ++s) acc[s] += Zt[s][i] * w;
        }
        #pragma unroll
        for (int s = 0; s < SPB1; ++s) {
            float h, sp, fpp;
            silu_derivs(acc[s], h, sp, fpp);
            Ha[t][s] = h;
            S[(0 * BS + m0 + s) * HID + t] = sp;
            f2a[0][s] = fpp;
        }
    }
    __syncthreads();
    fwd_layer(1, t, m0, Ha, Hb, W1, b1, f2a[1], S);  // h2
    __syncthreads();
    fwd_layer(2, t, m0, Hb, Ha, W2, b2, f2a[2], S);  // h3
    __syncthreads();
    // ---- layer 4 + start of backward ----
    {
        float acc[SPB1];
        #pragma unroll
        for (int s = 0; s < SPB1; ++s) acc[s] = b3[t];
        const float4* H4 = (const float4*)&Ha[0][0];
        #pragma unroll 8
        for (int i = 0; i < 256; ++i) {
            float w = W3[i * 256 + t];
            float4 h0 = H4[i * 2 + 0];
            float4 h1 = H4[i * 2 + 1];
            acc[0] += h0.x * w; acc[1] += h0.y * w; acc[2] += h0.z * w; acc[3] += h0.w * w;
            acc[4] += h1.x * w; acc[5] += h1.y * w; acc[6] += h1.z * w; acc[7] += h1.w * w;
        }
        float w4 = W4[t];
        #pragma unroll
        for (int s = 0; s < SPB1; ++s) {
            float h, sp, fpp;
            silu_derivs(acc[s], h, sp, fpp);
            Hb[t][s] = w4 * sp;                          // delta_a4
            C[(3 * BS + m0 + s) * HID + t] = w4 * fpp;   // c4
        }
    }
    __syncthreads();
    bwd_layer(2, t, m0, Hb, Ha, WT3, f2a[2], S, C);  // delta_a3 in Ha
    __syncthreads();
    bwd_layer(1, t, m0, Ha, Hb, WT2, f2a[1], S, C);  // delta_a2 in Hb
    __syncthreads();
    bwd_layer(0, t, m0, Hb, Ha, WT1, f2a[0], S, C);  // delta_a1 in Ha
    __syncthreads();
    // ---- gradient: g[k] = sum_i W0[k][i] * delta_a1[i] ----
    {
        const int k = t & 31, sh = t >> 5;
        float acc = 0.0f;
        #pragma unroll 4
        for (int i = 0; i < 256; ++i) acc += WT0[i * 32 + k] * Ha[i][sh];
        if (k < 16) G[(m0 + sh) * 16 + k] = acc;
    }
}

// ---------------- kernel 2: 8-wave 32x32 MFMA tangent propagation ----------------
// 1 sample/block, 512 threads = 8 waves; wave w owns ONE 32-col n-tile.
// R10 (512,4): VGPR 64 vs cap 128, 792 us, latency-stalled. R11: (512,6) ->
// cap ~85, 3 blocks/CU = 6 waves/SIMD (LDS 3x39.9 KB = 120 KB), plus restored
// next-phase C/S register prefetch (~+8 VGPR, two barriers guarantee arrival).
#define RS2 72    // shorts per slot row (144 B)
#define STP 68    // floats per staging row (stride ≡ 4 mod 32 banks)

__global__ __launch_bounds__(512, 6) void k_stage2(
    const float* __restrict__ z,
    const float* __restrict__ W0,
    const ushort* __restrict__ WBT,
    const float* __restrict__ S, const float* __restrict__ C, const float* __restrict__ G,
    float* __restrict__ out)
{
    // slots: 0=ASh 1=ASl 2=ACh 3=ACl 4=TPh 5=TPl  (each 32 x RS2 shorts)
    __shared__ __align__(16) ushort SMEM[6 * 32 * RS2];   // 27648 B
    __shared__ __align__(16) float stg[32 * STP];         // 8704 B
    __shared__ float HCl[32][16];
    __shared__ float Msys[16][17];
    __shared__ float vvs[16];
    // total ~39.6 KB -> 3 blocks/CU at (512,6)

    const int t    = threadIdx.x;   // 0..511
    const int m    = blockIdx.x;
    const int lane = t & 63;
    const int w    = t >> 6;        // wave 0..7
    const int ln   = lane & 31;
    const int hf   = lane >> 5;
    const int er   = t >> 4;        // epilogue row 0..31
    const int ej   = (t & 15) * 4;  // epilogue col offset 0,4,..60

#define SLOT(a) (&SMEM[(a) * 32 * RS2])

    f32x16 Tacc;   // this wave's T columns (32w + ln), MFMA C-layout
    f32x16 Tnxt;
    f32x16 Dacc;
    #pragma unroll
    for (int r = 0; r < 16; ++r) { Tacc[r] = 0.0f; Tnxt[r] = 0.0f; Dacc[r] = 0.0f; }

    // prefetch C/S for (lay=0, p=0)
    float4 cc = *(const float4*)&C[(0 * BS + m) * HID + ej];
    float4 sv = *(const float4*)&S[(0 * BS + m) * HID + ej];

    for (int lay = 0; lay < 4; ++lay) {
        for (int p = 0; p < 4; ++p) {
            // ---- issue next-phase C/S loads (consumed next phase after 2 barriers)
            float4 cn, sn;
            const int nlay = (p < 3) ? lay : lay + 1;
            const int np   = (p < 3) ? p + 1 : 0;
            if (nlay < 4) {
                cn = *(const float4*)&C[(nlay * BS + m) * HID + np * 64 + ej];
                if (nlay < 3)
                    sn = *(const float4*)&S[(nlay * BS + m) * HID + np * 64 + ej];
            }

            // ---------- epilogue: 512 threads x 4 elements ----------
            {
                float tv[4], tmp[4];
                if (lay == 0) {
                    *(float4*)tv = *(const float4*)&W0[er * HID + p * 64 + ej];
                } else {
                    *(float4*)tv = *(const float4*)&stg[er * STP + ej];
                }
                uint2 H, L;
                tmp[0] = cc.x * tv[0]; tmp[1] = cc.y * tv[1];
                tmp[2] = cc.z * tv[2]; tmp[3] = cc.w * tv[3];
                split4v(tmp, H, L);
                *(uint2*)(SLOT(2) + er * RS2 + ej) = H;
                *(uint2*)(SLOT(3) + er * RS2 + ej) = L;
                if (lay < 3) {
                    tmp[0] = sv.x * tv[0]; tmp[1] = sv.y * tv[1];
                    tmp[2] = sv.z * tv[2]; tmp[3] = sv.w * tv[3];
                    split4v(tmp, H, L);
                    *(uint2*)(SLOT(0) + er * RS2 + ej) = H;
                    *(uint2*)(SLOT(1) + er * RS2 + ej) = L;
                }
                if (er >= 16) {   // waves 4..7 — wave-uniform branch
                    split4v(tv, H, L);
                    *(uint2*)(SLOT(4) + (er - 16) * RS2 + ej) = H;
                    *(uint2*)(SLOT(5) + (er - 16) * RS2 + ej) = L;
                }
            }
            __syncthreads();

            // ---------- contraction: waves 0..3, wave w takes K-chunk w ----------
            if (w < 4) {
                const int ko = w * 16 + hf * 8;
                bf16x8 Bph = *(const bf16x8*)(SLOT(4) + ln * RS2 + ko);
                bf16x8 Bpl = *(const bf16x8*)(SLOT(5) + ln * RS2 + ko);
                bf16x8 Ah = *(const bf16x8*)(SLOT(2) + ln * RS2 + ko);
                bf16x8 Al = *(const bf16x8*)(SLOT(3) + ln * RS2 + ko);
                Dacc = MFMA32(Ah, Bph, MFMA32(Al, Bph, MFMA32(Ah, Bpl, Dacc)));
            }

            // ---------- GEMM: all 8 waves, wave w owns n-tile w ----------
            if (lay < 3) {
                #pragma unroll
                for (int ks = 0; ks < 4; ++ks) {
                    const int ko = ks * 16 + hf * 8;
                    const int kb = p * 4 + ks;
                    bf16x8 Ah = *(const bf16x8*)(SLOT(0) + ln * RS2 + ko);
                    bf16x8 Al = *(const bf16x8*)(SLOT(1) + ln * RS2 + ko);
                    bf16x8 Bh = *(const bf16x8*)&WBT[
                        (((lay * 2 + 0) * 128) + w * 16 + kb) * 512 + lane * 8];
                    bf16x8 Bl = *(const bf16x8*)&WBT[
                        (((lay * 2 + 1) * 128) + w * 16 + kb) * 512 + lane * 8];
                    Tnxt = MFMA32(Ah, Bh,
                           MFMA32(Al, Bh,
                           MFMA32(Ah, Bl, Tnxt)));
                }
            }

            // ---------- staging dump for the NEXT phase ----------
            {
                bool dumpNow = false, fromN = false;
                if (p < 3) { dumpNow = (lay > 0) && ((w >> 1) == p + 1); }
                else       { dumpNow = (lay < 3) && (w < 2); fromN = true; }
                if (dumpNow) {
                    #pragma unroll
                    for (int r = 0; r < 16; ++r) {
                        const int row = (r & 3) + 8 * (r >> 2) + 4 * hf;
                        stg[row * STP + (w & 1) * 32 + ln] = fromN ? Tnxt[r] : Tacc[r];
                    }
                }
            }
            __syncthreads();

            // ---- rotate prefetched C/S ----
            if (nlay < 4) {
                cc = cn;
                if (nlay < 3) sv = sn;
            }
        } // p

        // ---------- layer end: Tacc <- Tnxt (registers only) ----------
        if (lay < 3) {
            Tacc = Tnxt;
            #pragma unroll
            for (int r = 0; r < 16; ++r) Tnxt[r] = 0.0f;
        }
    } // lay

    // ---------- reduce Hessian partials (overlay on SMEM; only 16 valid cols) ---
    float* Dred = (float*)SMEM;   // [4][32][16] = 8 KB
    if (w < 4) {
        #pragma unroll
        for (int r = 0; r < 16; ++r) {
            const int row = (r & 3) + 8 * (r >> 2) + 4 * hf;
            if (ln < 16) Dred[(w * 32 + row) * 16 + ln] = Dacc[r];
        }
    }
    __syncthreads();

    // ---------- wave-0 reduce + solve ----------
    if (w == 0) {
        for (int idx = lane; idx < 512; idx += 64) {
            const int row = idx >> 4, j = idx & 15;
            HCl[row][j] = Dred[(0 * 32 + row) * 16 + j] + Dred[(1 * 32 + row) * 16 + j]
                        + Dred[(2 * 32 + row) * 16 + j] + Dred[(3 * 32 + row) * 16 + j];
        }

        float* M = &Msys[0][0];   // [16][17]
        float vr = 0.0f;
        if (lane < 16) {
            vr = z[m * 32 + 16 + lane];
            vvs[lane] = vr;
        }
        if (lane < 16) {
            #pragma unroll
            for (int j = 0; j < 16; ++j)
                M[lane * 17 + j] = HCl[16 + lane][j] + (lane == j ? 0.2f : 0.0f);
            float r = G[m * 16 + lane];
            #pragma unroll
            for (int j = 0; j < 16; ++j)
                r -= HCl[j][lane] * vvs[j];
            M[lane * 17 + 16] = r;
        }
        // Gauss-Jordan with partial pivoting (wave-synchronous)
        for (int k2 = 0; k2 < 16; ++k2) {
            float val = (lane < 16 && lane >= k2) ? fabsf(M[lane * 17 + k2]) : -1.0f;
            int idx = lane;
            #pragma unroll
            for (int off = 8; off > 0; off >>= 1) {
                float ov = __shfl_xor(val, off, 64);
                int oi = __shfl_xor(idx, off, 64);
                if (ov > val) { val = ov; idx = oi; }
            }
            const int p2 = __shfl(idx, 0, 64);
            if (p2 != k2 && lane < 17) {
                float tmp = M[k2 * 17 + lane];
                M[k2 * 17 + lane] = M[p2 * 17 + lane];
                M[p2 * 17 + lane] = tmp;
            }
            if (lane < 16) {
                const float f = (lane == k2) ? 0.0f : M[lane * 17 + k2] / M[k2 * 17 + k2];
                #pragma unroll
                for (int j = 0; j < 17; ++j)
                    M[lane * 17 + j] -= f * M[k2 * 17 + j];
            }
        }
        if (lane < 16) {
            out[m * 32 + lane]      = vr;
            out[m * 32 + 16 + lane] = M[lane * 17 + 16] / M[lane * 17 + lane];
        }
    }
#undef SLOT
}

extern "C" void kernel_launch(void* const* d_in, const int* in_sizes, int n_in,
                              void* d_out, int out_size, void* d_ws, size_t ws_size,
                              hipStream_t stream) {
    const float* z  = (const float*)d_in[1];
    const float* W0 = (const float*)d_in[2];
    const float* b0 = (const float*)d_in[3];
    const float* W1 = (const float*)d_in[4];
    const float* b1 = (const float*)d_in[5];
    const float* W2 = (const float*)d_in[6];
    const float* b2 = (const float*)d_in[7];
    const float* W3 = (const float*)d_in[8];
    const float* b3 = (const float*)d_in[9];
    const float* W4 = (const float*)d_in[10];
    float* out = (float*)d_out;
    float* ws  = (float*)d_ws;

    float* WT1 = ws + WT1_OFF;
    float* WT2 = ws + WT2_OFF;
    float* WT3 = ws + WT3_OFF;
    float* WT0 = ws + WT0_OFF;
    float* S   = ws + S_OFF;
    float* C   = ws + C_OFF;
    float* G   = ws + G_OFF;
    const ushort* WBT = (const ushort*)(ws + WBT_OFF);

    k_transpose<<<dim3(256, 4), 256, 0, stream>>>(W0, W1, W2, W3, ws);
    k_stage1<<<BS / SPB1, 256, 0, stream>>>(z, W0, b0, W1, b1, W2, b2, W3, b3, W4,
                                            WT0, WT1, WT2, WT3, S, C, G);
    k_stage2<<<BS, 512, 0, stream>>>(z, W0, WBT, S, C, G, out);
}

// Round 12
// 870.832 us; speedup vs baseline: 2.0119x; 2.0119x over previous
//
#include <hip/hip_runtime.h>
#include <hip/hip_bf16.h>
#include <math.h>

#define BS 8192
#define HID 256
#define SPB1 8

// ---- workspace layout (float element offsets) ----
#define WT1_OFF 0
#define WT2_OFF 65536
#define WT3_OFF 131072
#define WT0_OFF 196608
#define S_OFF   204800
#define C_OFF   (S_OFF + 4 * BS * HID)
#define G_OFF   (C_OFF + 4 * BS * HID)
#define WBT_OFF (G_OFF + BS * 16)
// WBT region: brick-swizzled W: 3 lay x 2 (hi,lo) x 8 nt x 16 kb x 64 lanes x 8 shorts

typedef __attribute__((ext_vector_type(8))) short bf16x8;
typedef __attribute__((ext_vector_type(16))) float f32x16;
#define MFMA32(A, B, C) __builtin_amdgcn_mfma_f32_32x32x16_bf16(A, B, C, 0, 0, 0)

__device__ __forceinline__ ushort bf16_rne(float x) {
    unsigned u = __float_as_uint(x);
    unsigned r = u + 0x7FFFu + ((u >> 16) & 1u);
    return (ushort)(r >> 16);
}
__device__ __forceinline__ void bsplit(float x, ushort& hi, ushort& lo) {
    hi = bf16_rne(x);
    float hf = __uint_as_float(((unsigned)hi) << 16);
    lo = bf16_rne(x - hf);
}

// packed split via v_cvt_pk_bf16_f32 (gfx950)
__device__ __forceinline__ uint pk2(float a, float b) {
    __hip_bfloat162 h = __float22bfloat162_rn(float2{a, b});
    uint u; __builtin_memcpy(&u, &h, 4); return u;
}
__device__ __forceinline__ void split2(float a, float b, uint& hp, uint& lp) {
    hp = pk2(a, b);
    float ha = __uint_as_float(hp << 16);
    float hb = __uint_as_float(hp & 0xFFFF0000u);
    lp = pk2(a - ha, b - hb);
}
__device__ __forceinline__ void split4v(const float* v, uint2& H, uint2& L) {
    split2(v[0], v[1], H.x, L.x);
    split2(v[2], v[3], H.y, L.y);
}

__device__ __forceinline__ void silu_derivs(float a, float& h, float& sp, float& fpp) {
    float sig = 1.0f / (1.0f + __expf(-a));
    float om  = 1.0f - sig;
    h   = a * sig;
    sp  = sig * (1.0f + a * om);                       // silu'
    fpp = sig * om * (2.0f + a * (1.0f - 2.0f * sig)); // silu''
}

// ---------------- kernel 0: weight transposes + bf16 brick swizzle ----------------
__global__ void k_transpose(const float* __restrict__ W0, const float* __restrict__ W1,
                            const float* __restrict__ W2, const float* __restrict__ W3,
                            float* __restrict__ ws) {
    float* WT1 = ws + WT1_OFF;
    float* WT2 = ws + WT2_OFF;
    float* WT3 = ws + WT3_OFF;
    float* WT0 = ws + WT0_OFF;
    ushort* WBT = (ushort*)(ws + WBT_OFF);
    int o = blockIdx.x;      // 0..255 (output col)
    int t = threadIdx.x;     // 0..255 (input row k)
    int which = blockIdx.y;  // 0..3
    if (which < 3) {
        const float* W = (which == 0) ? W1 : (which == 1) ? W2 : W3;
        float* WT = (which == 0) ? WT1 : (which == 1) ? WT2 : WT3;
        float v = W[t * 256 + o];
        WT[o * 256 + t] = v;
        ushort h, l;
        bsplit(v, h, l);
        const int ntg = o >> 5, ln0 = o & 31;
        const int kb = t >> 4, hfb = (t >> 3) & 1, j = t & 7;
        const int laneidx = ln0 + 32 * hfb;
        WBT[(((which * 2 + 0) * 128) + ntg * 16 + kb) * 512 + laneidx * 8 + j] = h;
        WBT[(((which * 2 + 1) * 128) + ntg * 16 + kb) * 512 + laneidx * 8 + j] = l;
    } else if (t < 32) {
        WT0[o * 32 + t] = W0[t * 256 + o]; // WT0[i][k] = W0[k][i]
    }
}

// ---------------- kernel 1: forward + backward (8 samples/block) ----------------
__device__ __forceinline__ void fwd_layer(int L, int t, int m0,
        const float (*Hin)[SPB1], float (*Hout)[SPB1],
        const float* __restrict__ W, const float* __restrict__ b,
        float* __restrict__ f2, float* __restrict__ S)
{
    float acc[SPB1];
    #pragma unroll
    for (int s = 0; s < SPB1; ++s) acc[s] = b[t];
    const float4* H4 = (const float4*)&Hin[0][0];
    #pragma unroll 8
    for (int i = 0; i < 256; ++i) {
        float w = W[i * 256 + t];
        float4 h0 = H4[i * 2 + 0];
        float4 h1 = H4[i * 2 + 1];
        acc[0] += h0.x * w; acc[1] += h0.y * w; acc[2] += h0.z * w; acc[3] += h0.w * w;
        acc[4] += h1.x * w; acc[5] += h1.y * w; acc[6] += h1.z * w; acc[7] += h1.w * w;
    }
    #pragma unroll
    for (int s = 0; s < SPB1; ++s) {
        float h, sp, fpp;
        silu_derivs(acc[s], h, sp, fpp);
        Hout[t][s] = h;
        S[(L * BS + m0 + s) * HID + t] = sp;
        f2[s] = fpp;
    }
}

__device__ __forceinline__ void bwd_layer(int L, int t, int m0,
        const float (*Din)[SPB1], float (*Dout)[SPB1],
        const float* __restrict__ WT,
        const float* __restrict__ f2,
        const float* __restrict__ S, float* __restrict__ C)
{
    float acc[SPB1];
    #pragma unroll
    for (int s = 0; s < SPB1; ++s) acc[s] = 0.0f;
    const float4* D4 = (const float4*)&Din[0][0];
    #pragma unroll 8
    for (int o = 0; o < 256; ++o) {
        float w = WT[o * 256 + t];
        float4 d0 = D4[o * 2 + 0];
        float4 d1 = D4[o * 2 + 1];
        acc[0] += d0.x * w; acc[1] += d0.y * w; acc[2] += d0.z * w; acc[3] += d0.w * w;
        acc[4] += d1.x * w; acc[5] += d1.y * w; acc[6] += d1.z * w; acc[7] += d1.w * w;
    }
    #pragma unroll
    for (int s = 0; s < SPB1; ++s) {
        float dh = acc[s];
        float sl = S[(L * BS + m0 + s) * HID + t];
        C[(L * BS + m0 + s) * HID + t] = dh * f2[s];
        Dout[t][s] = dh * sl;  // delta_a
    }
}

__global__ __launch_bounds__(256) void k_stage1(
    const float* __restrict__ z,
    const float* __restrict__ W0, const float* __restrict__ b0,
    const float* __restrict__ W1, const float* __restrict__ b1,
    const float* __restrict__ W2, const float* __restrict__ b2,
    const float* __restrict__ W3, const float* __restrict__ b3,
    const float* __restrict__ W4,
    const float* __restrict__ WT0, const float* __restrict__ WT1,
    const float* __restrict__ WT2, const float* __restrict__ WT3,
    float* __restrict__ S, float* __restrict__ C, float* __restrict__ G)
{
    __shared__ __align__(16) float Zt[SPB1][32];
    __shared__ __align__(16) float Ha[256][SPB1];
    __shared__ __align__(16) float Hb[256][SPB1];
    const int t  = threadIdx.x;
    const int m0 = blockIdx.x * SPB1;
    float f2a[3][SPB1];   // silu'' layers 0..2: same-thread produce/consume

    Zt[t >> 5][t & 31] = z[(m0 + (t >> 5)) * 32 + (t & 31)];
    __syncthreads();

    // ---- layer 1: a1 = z @ W0 + b0 ----
    {
        float acc[SPB1];
        #pragma unroll
        for (int s = 0; s < SPB1; ++s) acc[s] = b0[t];
        #pragma unroll 8
        for (int i = 0; i < 32; ++i) {
            float w = W0[i * 256 + t];
            #pragma unroll
            for (int s = 0; s < SPB1; ++s) acc[s] += Zt[s][i] * w;
        }
        #pragma unroll
        for (int s = 0; s < SPB1; ++s) {
            float h, sp, fpp;
            silu_derivs(acc[s], h, sp, fpp);
            Ha[t][s] = h;
            S[(0 * BS + m0 + s) * HID + t] = sp;
            f2a[0][s] = fpp;
        }
    }
    __syncthreads();
    fwd_layer(1, t, m0, Ha, Hb, W1, b1, f2a[1], S);  // h2
    __syncthreads();
    fwd_layer(2, t, m0, Hb, Ha, W2, b2, f2a[2], S);  // h3
    __syncthreads();
    // ---- layer 4 + start of backward ----
    {
        float acc[SPB1];
        #pragma unroll
        for (int s = 0; s < SPB1; ++s) acc[s] = b3[t];
        const float4* H4 = (const float4*)&Ha[0][0];
        #pragma unroll 8
        for (int i = 0; i < 256; ++i) {
            float w = W3[i * 256 + t];
            float4 h0 = H4[i * 2 + 0];
            float4 h1 = H4[i * 2 + 1];
            acc[0] += h0.x * w; acc[1] += h0.y * w; acc[2] += h0.z * w; acc[3] += h0.w * w;
            acc[4] += h1.x * w; acc[5] += h1.y * w; acc[6] += h1.z * w; acc[7] += h1.w * w;
        }
        float w4 = W4[t];
        #pragma unroll
        for (int s = 0; s < SPB1; ++s) {
            float h, sp, fpp;
            silu_derivs(acc[s], h, sp, fpp);
            Hb[t][s] = w4 * sp;                          // delta_a4
            C[(3 * BS + m0 + s) * HID + t] = w4 * fpp;   // c4
        }
    }
    __syncthreads();
    bwd_layer(2, t, m0, Hb, Ha, WT3, f2a[2], S, C);  // delta_a3 in Ha
    __syncthreads();
    bwd_layer(1, t, m0, Ha, Hb, WT2, f2a[1], S, C);  // delta_a2 in Hb
    __syncthreads();
    bwd_layer(0, t, m0, Hb, Ha, WT1, f2a[0], S, C);  // delta_a1 in Ha
    __syncthreads();
    // ---- gradient: g[k] = sum_i W0[k][i] * delta_a1[i] ----
    {
        const int k = t & 31, sh = t >> 5;
        float acc = 0.0f;
        #pragma unroll 4
        for (int i = 0; i < 256; ++i) acc += WT0[i * 32 + k] * Ha[i][sh];
        if (k < 16) G[(m0 + sh) * 16 + k] = acc;
    }
}

// ---------------- kernel 2: 8-wave 32x32 MFMA tangent propagation ----------------
// 1 sample/block, 512 threads = 8 waves; wave w owns ONE 32-col n-tile.
// Config law from R8/R9/R11: natural footprint ~64-100 VGPR; any launch_bounds
// cap below that spills to scratch (GB-scale FETCH/WRITE). (512,4) = 128-reg cap
// is the proven-clean point (R10: VGPR 64, zero spill, 792 us). R12 adds, under
// that cap: next-phase C/S register prefetch + ks=0,1 brick hoist (B-frag L2
// latency covered by epilogue VALU).
#define RS2 72    // shorts per slot row (144 B)
#define STP 68    // floats per staging row (stride ≡ 4 mod 32 banks)

__global__ __launch_bounds__(512, 4) void k_stage2(
    const float* __restrict__ z,
    const float* __restrict__ W0,
    const ushort* __restrict__ WBT,
    const float* __restrict__ S, const float* __restrict__ C, const float* __restrict__ G,
    float* __restrict__ out)
{
    // slots: 0=ASh 1=ASl 2=ACh 3=ACl 4=TPh 5=TPl  (each 32 x RS2 shorts)
    __shared__ __align__(16) ushort SMEM[6 * 32 * RS2];   // 27648 B
    __shared__ __align__(16) float stg[32 * STP];         // 8704 B
    __shared__ float HCl[32][16];
    __shared__ float Msys[16][17];
    __shared__ float vvs[16];
    // total ~39.6 KB -> 2 blocks/CU at (512,4)

    const int t    = threadIdx.x;   // 0..511
    const int m    = blockIdx.x;
    const int lane = t & 63;
    const int w    = t >> 6;        // wave 0..7
    const int ln   = lane & 31;
    const int hf   = lane >> 5;
    const int er   = t >> 4;        // epilogue row 0..31
    const int ej   = (t & 15) * 4;  // epilogue col offset 0,4,..60

#define SLOT(a) (&SMEM[(a) * 32 * RS2])

    f32x16 Tacc;   // this wave's T columns (32w + ln), MFMA C-layout
    f32x16 Tnxt;
    f32x16 Dacc;
    #pragma unroll
    for (int r = 0; r < 16; ++r) { Tacc[r] = 0.0f; Tnxt[r] = 0.0f; Dacc[r] = 0.0f; }

    // prefetch C/S for (lay=0, p=0)
    float4 cc = *(const float4*)&C[(0 * BS + m) * HID + ej];
    float4 sv = *(const float4*)&S[(0 * BS + m) * HID + ej];

    for (int lay = 0; lay < 4; ++lay) {
        for (int p = 0; p < 4; ++p) {
            // ---- issue next-phase C/S loads (consumed next phase after 2 barriers)
            float4 cn, sn;
            const int nlay = (p < 3) ? lay : lay + 1;
            const int np   = (p < 3) ? p + 1 : 0;
            if (nlay < 4) {
                cn = *(const float4*)&C[(nlay * BS + m) * HID + np * 64 + ej];
                if (nlay < 3)
                    sn = *(const float4*)&S[(nlay * BS + m) * HID + np * 64 + ej];
            }

            // ---- hoisted brick loads for ks=0,1 (latency covered by epilogue) ----
            bf16x8 Bh01[2], Bl01[2];
            if (lay < 3) {
                #pragma unroll
                for (int ks = 0; ks < 2; ++ks) {
                    const int kb = p * 4 + ks;
                    Bh01[ks] = *(const bf16x8*)&WBT[
                        (((lay * 2 + 0) * 128) + w * 16 + kb) * 512 + lane * 8];
                    Bl01[ks] = *(const bf16x8*)&WBT[
                        (((lay * 2 + 1) * 128) + w * 16 + kb) * 512 + lane * 8];
                }
            }

            // ---------- epilogue: 512 threads x 4 elements ----------
            {
                float tv[4], tmp[4];
                if (lay == 0) {
                    *(float4*)tv = *(const float4*)&W0[er * HID + p * 64 + ej];
                } else {
                    *(float4*)tv = *(const float4*)&stg[er * STP + ej];
                }
                uint2 H, L;
                tmp[0] = cc.x * tv[0]; tmp[1] = cc.y * tv[1];
                tmp[2] = cc.z * tv[2]; tmp[3] = cc.w * tv[3];
                split4v(tmp, H, L);
                *(uint2*)(SLOT(2) + er * RS2 + ej) = H;
                *(uint2*)(SLOT(3) + er * RS2 + ej) = L;
                if (lay < 3) {
                    tmp[0] = sv.x * tv[0]; tmp[1] = sv.y * tv[1];
                    tmp[2] = sv.z * tv[2]; tmp[3] = sv.w * tv[3];
                    split4v(tmp, H, L);
                    *(uint2*)(SLOT(0) + er * RS2 + ej) = H;
                    *(uint2*)(SLOT(1) + er * RS2 + ej) = L;
                }
                if (er >= 16) {   // waves 4..7 — wave-uniform branch
                    split4v(tv, H, L);
                    *(uint2*)(SLOT(4) + (er - 16) * RS2 + ej) = H;
                    *(uint2*)(SLOT(5) + (er - 16) * RS2 + ej) = L;
                }
            }
            __syncthreads();

            // ---------- contraction: waves 0..3, wave w takes K-chunk w ----------
            if (w < 4) {
                const int ko = w * 16 + hf * 8;
                bf16x8 Bph = *(const bf16x8*)(SLOT(4) + ln * RS2 + ko);
                bf16x8 Bpl = *(const bf16x8*)(SLOT(5) + ln * RS2 + ko);
                bf16x8 Ah = *(const bf16x8*)(SLOT(2) + ln * RS2 + ko);
                bf16x8 Al = *(const bf16x8*)(SLOT(3) + ln * RS2 + ko);
                Dacc = MFMA32(Ah, Bph, MFMA32(Al, Bph, MFMA32(Ah, Bpl, Dacc)));
            }

            // ---------- GEMM: all 8 waves, wave w owns n-tile w ----------
            if (lay < 3) {
                #pragma unroll
                for (int ks = 0; ks < 4; ++ks) {
                    const int ko = ks * 16 + hf * 8;
                    const int kb = p * 4 + ks;
                    bf16x8 Ah = *(const bf16x8*)(SLOT(0) + ln * RS2 + ko);
                    bf16x8 Al = *(const bf16x8*)(SLOT(1) + ln * RS2 + ko);
                    bf16x8 Bh, Bl;
                    if (ks < 2) { Bh = Bh01[ks]; Bl = Bl01[ks]; }
                    else {
                        Bh = *(const bf16x8*)&WBT[
                            (((lay * 2 + 0) * 128) + w * 16 + kb) * 512 + lane * 8];
                        Bl = *(const bf16x8*)&WBT[
                            (((lay * 2 + 1) * 128) + w * 16 + kb) * 512 + lane * 8];
                    }
                    Tnxt = MFMA32(Ah, Bh,
                           MFMA32(Al, Bh,
                           MFMA32(Ah, Bl, Tnxt)));
                }
            }

            // ---------- staging dump for the NEXT phase ----------
            {
                bool dumpNow = false, fromN = false;
                if (p < 3) { dumpNow = (lay > 0) && ((w >> 1) == p + 1); }
                else       { dumpNow = (lay < 3) && (w < 2); fromN = true; }
                if (dumpNow) {
                    #pragma unroll
                    for (int r = 0; r < 16; ++r) {
                        const int row = (r & 3) + 8 * (r >> 2) + 4 * hf;
                        stg[row * STP + (w & 1) * 32 + ln] = fromN ? Tnxt[r] : Tacc[r];
                    }
                }
            }
            __syncthreads();

            // ---- rotate prefetched C/S ----
            if (nlay < 4) {
                cc = cn;
                if (nlay < 3) sv = sn;
            }
        } // p

        // ---------- layer end: Tacc <- Tnxt (registers only) ----------
        if (lay < 3) {
            Tacc = Tnxt;
            #pragma unroll
            for (int r = 0; r < 16; ++r) Tnxt[r] = 0.0f;
        }
    } // lay

    // ---------- reduce Hessian partials (overlay on SMEM; only 16 valid cols) ---
    float* Dred = (float*)SMEM;   // [4][32][16] = 8 KB
    if (w < 4) {
        #pragma unroll
        for (int r = 0; r < 16; ++r) {
            const int row = (r & 3) + 8 * (r >> 2) + 4 * hf;
            if (ln < 16) Dred[(w * 32 + row) * 16 + ln] = Dacc[r];
        }
    }
    __syncthreads();

    // ---------- wave-0 reduce + solve ----------
    if (w == 0) {
        for (int idx = lane; idx < 512; idx += 64) {
            const int row = idx >> 4, j = idx & 15;
            HCl[row][j] = Dred[(0 * 32 + row) * 16 + j] + Dred[(1 * 32 + row) * 16 + j]
                        + Dred[(2 * 32 + row) * 16 + j] + Dred[(3 * 32 + row) * 16 + j];
        }

        float* M = &Msys[0][0];   // [16][17]
        float vr = 0.0f;
        if (lane < 16) {
            vr = z[m * 32 + 16 + lane];
            vvs[lane] = vr;
        }
        if (lane < 16) {
            #pragma unroll
            for (int j = 0; j < 16; ++j)
                M[lane * 17 + j] = HCl[16 + lane][j] + (lane == j ? 0.2f : 0.0f);
            float r = G[m * 16 + lane];
            #pragma unroll
            for (int j = 0; j < 16; ++j)
                r -= HCl[j][lane] * vvs[j];
            M[lane * 17 + 16] = r;
        }
        // Gauss-Jordan with partial pivoting (wave-synchronous)
        for (int k2 = 0; k2 < 16; ++k2) {
            float val = (lane < 16 && lane >= k2) ? fabsf(M[lane * 17 + k2]) : -1.0f;
            int idx = lane;
            #pragma unroll
            for (int off = 8; off > 0; off >>= 1) {
                float ov = __shfl_xor(val, off, 64);
                int oi = __shfl_xor(idx, off, 64);
                if (ov > val) { val = ov; idx = oi; }
            }
            const int p2 = __shfl(idx, 0, 64);
            if (p2 != k2 && lane < 17) {
                float tmp = M[k2 * 17 + lane];
                M[k2 * 17 + lane] = M[p2 * 17 + lane];
                M[p2 * 17 + lane] = tmp;
            }
            if (lane < 16) {
                const float f = (lane == k2) ? 0.0f : M[lane * 17 + k2] / M[k2 * 17 + k2];
                #pragma unroll
                for (int j = 0; j < 17; ++j)
                    M[lane * 17 + j] -= f * M[k2 * 17 + j];
            }
        }
        if (lane < 16) {
            out[m * 32 + lane]      = vr;
            out[m * 32 + 16 + lane] = M[lane * 17 + 16] / M[lane * 17 + lane];
        }
    }
#undef SLOT
}

extern "C" void kernel_launch(void* const* d_in, const int* in_sizes, int n_in,
                              void* d_out, int out_size, void* d_ws, size_t ws_size,
                              hipStream_t stream) {
    const float* z  = (const float*)d_in[1];
    const float* W0 = (const float*)d_in[2];
    const float* b0 = (const float*)d_in[3];
    const float* W1 = (const float*)d_in[4];
    const float* b1 = (const float*)d_in[5];
    const float* W2 = (const float*)d_in[6];
    const float* b2 = (const float*)d_in[7];
    const float* W3 = (const float*)d_in[8];
    const float* b3 = (const float*)d_in[9];
    const float* W4 = (const float*)d_in[10];
    float* out = (float*)d_out;
    float* ws  = (float*)d_ws;

    float* WT1 = ws + WT1_OFF;
    float* WT2 = ws + WT2_OFF;
    float* WT3 = ws + WT3_OFF;
    float* WT0 = ws + WT0_OFF;
    float* S   = ws + S_OFF;
    float* C   = ws + C_OFF;
    float* G   = ws + G_OFF;
    const ushort* WBT = (const ushort*)(ws + WBT_OFF);

    k_transpose<<<dim3(256, 4), 256, 0, stream>>>(W0, W1, W2, W3, ws);
    k_stage1<<<BS / SPB1, 256, 0, stream>>>(z, W0, b0, W1, b1, W2, b2, W3, b3, W4,
                                            WT0, WT1, WT2, WT3, S, C, G);
    k_stage2<<<BS, 512, 0, stream>>>(z, W0, WBT, S, C, G, out);
}